// Round 10
// baseline (250.778 us; speedup 1.0000x reference)
//
#include <hip/hip_runtime.h>
#include <math.h>

#define N_NODES 50000
#define N_EDGES 800000
#define ET (N_EDGES + N_NODES)   // 850000 incl. self-loops
#define KD 128
#define Z 32
#define SH 7
#define BW 128                              // nodes per bucket
#define NBUCK ((N_NODES + BW - 1) / BW)     // 391
#define CHUNK 4096
#define NBLKA ((ET + CHUNK - 1) / CHUNK)    // 208 chunks
#define MTOT (NBUCK * NBLKA)                // 81,328
#define MBS ((MTOT + 1023) / 1024)          // 80
#define WCB 64                              // wconv blocks
#define MM2B ((N_NODES + 63) / 64)          // 782 mmt2 blocks
#define WCE ((ET + 255) / 256)              // 3321 wcalc blocks

typedef __attribute__((ext_vector_type(8))) short bf16x8;
typedef __attribute__((ext_vector_type(4))) float f32x4;
typedef __attribute__((ext_vector_type(4))) int i32x4;
typedef __attribute__((ext_vector_type(4))) unsigned u32x4;

static __device__ __forceinline__ float lrelu(float x){ return x > 0.f ? x : 0.2f*x; }
static __device__ __forceinline__ float lof(unsigned int u){ return __uint_as_float(u << 16); }
static __device__ __forceinline__ float hif(unsigned int u){ return __uint_as_float(u & 0xffff0000u); }
static __device__ __forceinline__ unsigned short f2bf(float f){
  unsigned int x = __float_as_uint(f);
  return (unsigned short)((x + 0x7fffu + ((x >> 16) & 1u)) >> 16);   // RNE
}
static __device__ __forceinline__ unsigned int pack2(float lo, float hi){
  return (unsigned int)f2bf(lo) | ((unsigned int)f2bf(hi) << 16);
}
// cached gather load: base(SGPR) + unsigned byte offset
static __device__ __forceinline__ uint4 ld16u(const void* base, unsigned boff){
  return *(const uint4*)((const char*)base + boff);
}
// non-temporal (streaming) 16B load/store — read-once / write-once data
static __device__ __forceinline__ i32x4 ldnt(const void* base, unsigned boff){
  return __builtin_nontemporal_load((const i32x4*)((const char*)base + boff));
}
static __device__ __forceinline__ void stnt(void* base, unsigned boff, i32x4 v){
  __builtin_nontemporal_store(v, (i32x4*)((char*)base + boff));
}

// ---------- bodies for packed kernels ----------
static __device__ __forceinline__ void bhistA_body(int k, const int* __restrict__ edges, int* __restrict__ M){
  int t = threadIdx.x;
  __shared__ int cnt[NBUCK];
  for(int b = t; b < NBUCK; b += 256) cnt[b] = 0;
  __syncthreads();
  int base = k*CHUNK;
  int lim = min(base + CHUNK, ET);
  for(int i = base + t; i < lim; i += 256){
    int d = (i < N_EDGES) ? edges[N_EDGES + i] : (i - N_EDGES);
    atomicAdd(&cnt[d >> SH], 1);
  }
  __syncthreads();
  for(int b = t; b < NBUCK; b += 256) M[b*NBLKA + k] = cnt[b];
}

static __device__ __forceinline__ void wconv_body(int bid, const float* __restrict__ W1,
                                                  const float* __restrict__ Wmu, const float* __restrict__ Wst,
                                                  unsigned short* __restrict__ Wb1, unsigned short* __restrict__ Wb2,
                                                  int4* __restrict__ erec){
  int i = bid*256 + threadIdx.x;
  if(i < 128*KD) Wb1[i] = f2bf(W1[i]);
  if(i < 64*KD) Wb2[i] = f2bf(i < 32*KD ? Wmu[i] : Wst[i - 32*KD]);
  if(i < 32) erec[ET + i] = make_int4(0,0,0,0);   // zero pad: agg kernels overread up to +16
}

// va[k] = sum_z a[z] * W[z*128+k]  (alpha-2 folded vectors: (h W^T) a == h (W^T a))
static __device__ __forceinline__ void vacalc_body(const float* __restrict__ Wmu, const float* __restrict__ Wst,
                                                   const float* __restrict__ asmu, const float* __restrict__ admu,
                                                   const float* __restrict__ asst, const float* __restrict__ adst,
                                                   float* __restrict__ va){
  int k = threadIdx.x;
  if(k >= 128) return;
  float smu = 0.f, dmu = 0.f, sst = 0.f, dst = 0.f;
  #pragma unroll 8
  for(int z = 0; z < Z; z++){
    float wm = Wmu[z*128 + k], ws = Wst[z*128 + k];
    smu += asmu[z]*wm; dmu += admu[z]*wm;
    sst += asst[z]*ws; dst += adst[z]*ws;
  }
  va[k] = smu; va[128 + k] = dmu; va[256 + k] = sst; va[384 + k] = dst;
}

// packA: bhistA (208) || wconv (64) || vacalc (1)
__global__ __launch_bounds__(256) void packA_kernel(const int* __restrict__ edges, int* __restrict__ M,
                                                    const float* __restrict__ W1,
                                                    const float* __restrict__ Wmu, const float* __restrict__ Wst,
                                                    unsigned short* __restrict__ Wb1, unsigned short* __restrict__ Wb2,
                                                    int4* __restrict__ erec,
                                                    const float* __restrict__ asmu, const float* __restrict__ admu,
                                                    const float* __restrict__ asst, const float* __restrict__ adst,
                                                    float* __restrict__ va){
  if(blockIdx.x < NBLKA)            bhistA_body(blockIdx.x, edges, M);
  else if(blockIdx.x < NBLKA + WCB) wconv_body(blockIdx.x - NBLKA, W1, Wmu, Wst, Wb1, Wb2, erec);
  else                              vacalc_body(Wmu, Wst, asmu, admu, asst, adst, va);
}

__global__ __launch_bounds__(256) void scanM1_kernel(const int* __restrict__ M, int* __restrict__ bsumM){
  int b = blockIdx.x, t = threadIdx.x;
  int base = b*1024 + t*4;
  int s = 0;
  #pragma unroll
  for(int i=0;i<4;i++){ int n = base+i; if(n < MTOT) s += M[n]; }
  for(int off=32; off; off>>=1) s += __shfl_xor(s, off);
  __shared__ int ws[4];
  if((t&63)==0) ws[t>>6] = s;
  __syncthreads();
  if(t==0) bsumM[b] = ws[0]+ws[1]+ws[2]+ws[3];
}

// scanM3 with scanM2 folded in: each block computes its own bsumM prefix
__global__ __launch_bounds__(256) void scanM23_kernel(const int* __restrict__ M, const int* __restrict__ bsumM,
                                                      int* __restrict__ Mpos){
  int b = blockIdx.x, t = threadIdx.x;
  int lane = t & 63, wv = t >> 6;
  __shared__ int wsum[4];
  int pv = (t < b && t < MBS) ? bsumM[t] : 0;
  for(int off=32; off; off>>=1) pv += __shfl_xor(pv, off);
  if(lane == 0) wsum[wv] = pv;
  __syncthreads();
  int bpre = wsum[0] + wsum[1] + wsum[2] + wsum[3];
  int base = b*1024 + t*4;
  int d[4]; int s = 0;
  #pragma unroll
  for(int i=0;i<4;i++){ int n = base+i; d[i] = (n < MTOT) ? M[n] : 0; s += d[i]; }
  int v = s;
  for(int off=1; off<64; off<<=1){
    int u = __shfl_up(v, off);
    if(lane >= off) v += u;
  }
  int texcl = v - s;
  __shared__ int wtot[4];
  if(lane == 63) wtot[wv] = v;
  __syncthreads();
  int woff = 0;
  for(int i=0;i<wv;i++) woff += wtot[i];
  int run = bpre + woff + texcl;
  #pragma unroll
  for(int i=0;i<4;i++){
    int n = base+i;
    if(n < MTOT){ Mpos[n] = run; run += d[i]; }
  }
}

// bplaceA body: etmp entry packed as src(17b) | lo7(d)<<17; edges last read -> nontemporal
static __device__ __forceinline__ void bplaceA_body(int k, const int* __restrict__ edges,
                                                    const int* __restrict__ Mpos, unsigned int* __restrict__ etmp){
  int t = threadIdx.x;
  __shared__ int cur[NBUCK];
  for(int b = t; b < NBUCK; b += 256) cur[b] = Mpos[b*NBLKA + k];
  __syncthreads();
  int base = k*CHUNK;
  int lim = min(base + CHUNK, ET);
  for(int i = base + t; i < lim; i += 256){
    int s, d;
    if(i < N_EDGES){
      s = __builtin_nontemporal_load(&edges[i]);
      d = __builtin_nontemporal_load(&edges[N_EDGES+i]);
    } else { s = d = i - N_EDGES; }
    int pos = atomicAdd(&cur[d >> SH], 1);
    etmp[pos] = (unsigned int)s | ((unsigned int)(d & (BW-1)) << 17);
  }
}

// ---------- MFMA matmul layer1 body (OC=128) + fused alpha1; X read-once -> nontemporal ----------
static __device__ __forceinline__ void mmt1_body(int bid, const float* __restrict__ X,
                                                 const unsigned short* __restrict__ Wb,
                                                 const float* __restrict__ asv, const float* __restrict__ adv,
                                                 unsigned short* __restrict__ outb,
                                                 float* __restrict__ as1, float* __restrict__ ad1){
  constexpr int OC = 128, CT = 8;
  int t = threadIdx.x;
  int w = t >> 6, L = t & 63;
  int col = L & 15, quad = L >> 4;
  int row0 = bid*64 + w*16;
  int rA = row0 + col;
  if(rA >= N_NODES) rA = N_NODES-1;

  f32x4 acc[CT];
  #pragma unroll
  for(int ct=0;ct<CT;ct++) acc[ct] = (f32x4){0.f,0.f,0.f,0.f};

  #pragma unroll
  for(int kc=0;kc<4;kc++){
    int k0 = kc*32 + quad*8;
    const float* Xf = X + (size_t)rA*KD + k0;
    f32x4 p = __builtin_nontemporal_load((const f32x4*)Xf);
    f32x4 q = __builtin_nontemporal_load((const f32x4*)(Xf + 4));
    bf16x8 a;
    a[0] = (short)f2bf(p[0]); a[1] = (short)f2bf(p[1]);
    a[2] = (short)f2bf(p[2]); a[3] = (short)f2bf(p[3]);
    a[4] = (short)f2bf(q[0]); a[5] = (short)f2bf(q[1]);
    a[6] = (short)f2bf(q[2]); a[7] = (short)f2bf(q[3]);
    #pragma unroll
    for(int ct=0;ct<CT;ct++){
      bf16x8 b = *(const bf16x8*)(Wb + (size_t)(ct*16 + col)*KD + k0);
      acc[ct] = __builtin_amdgcn_mfma_f32_16x16x32_bf16(a, b, acc[ct], 0, 0, 0);
    }
  }

  float av[CT], dv[CT];
  #pragma unroll
  for(int ct=0;ct<CT;ct++){ av[ct] = asv[ct*16 + col]; dv[ct] = adv[ct*16 + col]; }

  #pragma unroll
  for(int r=0;r<4;r++){
    int row = row0 + quad*4 + r;
    #pragma unroll
    for(int ct=0;ct<CT;ct++)
      if(row < N_NODES) outb[(size_t)row*OC + ct*16 + col] = f2bf(acc[ct][r]);
    float s0 = acc[0][r]*av[0] + acc[1][r]*av[1] + acc[2][r]*av[2] + acc[3][r]*av[3];
    float s1 = acc[4][r]*av[4] + acc[5][r]*av[5] + acc[6][r]*av[6] + acc[7][r]*av[7];
    float d0 = acc[0][r]*dv[0] + acc[1][r]*dv[1] + acc[2][r]*dv[2] + acc[3][r]*dv[3];
    float d1 = acc[4][r]*dv[4] + acc[5][r]*dv[5] + acc[6][r]*dv[6] + acc[7][r]*dv[7];
    #pragma unroll
    for(int off=1; off<16; off<<=1){
      s0 += __shfl_xor(s0, off); s1 += __shfl_xor(s1, off);
      d0 += __shfl_xor(d0, off); d1 += __shfl_xor(d1, off);
    }
    if(col == 0 && row < N_NODES){
      as1[row*2] = s0; as1[row*2+1] = s1;
      ad1[row*2] = d0; ad1[row*2+1] = d1;
    }
  }
}

// packB: bplaceA (208) || mmt1 (782)
__global__ __launch_bounds__(256) void packB_kernel(const int* __restrict__ edges, const int* __restrict__ Mpos,
                                                    unsigned int* __restrict__ etmp,
                                                    const float* __restrict__ X, const unsigned short* __restrict__ Wb,
                                                    const float* __restrict__ asv, const float* __restrict__ adv,
                                                    unsigned short* __restrict__ outb,
                                                    float* __restrict__ as1, float* __restrict__ ad1){
  if(blockIdx.x < NBLKA) bplaceA_body(blockIdx.x, edges, Mpos, etmp);
  else                   mmt1_body(blockIdx.x - NBLKA, X, Wb, asv, adv, outb, as1, ad1);
}

// fused: bucket histogram + scan -> rowptr + place -> erec {src,dst,w1x,w1y} (wcalc1 fused)
// erec store is write-once stream -> nontemporal (keeps L2 free for agg gather table)
__global__ __launch_bounds__(256) void bfin_kernel(const int* __restrict__ Mpos, const unsigned int* __restrict__ etmp,
                                                   int* __restrict__ rowptr, int4* __restrict__ erec,
                                                   const float* __restrict__ as1, const float* __restrict__ ad1){
  int b = blockIdx.x, t = threadIdx.x;
  __shared__ int cnt[BW];
  __shared__ int pre[BW];
  __shared__ int lcur[BW];
  __shared__ float2 adl[BW];
  if(t < BW){
    cnt[t] = 0;
    int node = b*BW + t;
    adl[t] = (node < N_NODES) ? ((const float2*)ad1)[node] : make_float2(0.f, 0.f);
  }
  __syncthreads();
  int beg = Mpos[b*NBLKA];
  int end = (b+1 < NBUCK) ? Mpos[(b+1)*NBLKA] : ET;
  for(int i = beg + t; i < end; i += 256) atomicAdd(&cnt[etmp[i] >> 17], 1);
  __syncthreads();
  if(t < BW) pre[t] = cnt[t];
  __syncthreads();
  for(int off=1; off<BW; off<<=1){
    int u = 0;
    if(t < BW && t >= off) u = pre[t-off];
    __syncthreads();
    if(t < BW) pre[t] += u;
    __syncthreads();
  }
  if(t < BW){
    int excl = pre[t] - cnt[t];
    int node = b*BW + t;
    if(node < N_NODES) rowptr[node] = beg + excl;
    lcur[t] = beg + excl;
  }
  if(b == 0 && t == 255) rowptr[N_NODES] = ET;
  __syncthreads();
  const float2* asp = (const float2*)as1;
  for(int i = beg + t; i < end; i += 256){
    unsigned int e = etmp[i];
    int lo = (int)(e >> 17);
    int s  = (int)(e & 0x1FFFFu);
    int pos = atomicAdd(&lcur[lo], 1);
    float2 a = asp[s];
    float2 dd = adl[lo];
    i32x4 rec;
    rec[0] = s;
    rec[1] = b*BW + lo;
    rec[2] = __float_as_int(__expf(lrelu(a.x + dd.x)));
    rec[3] = __float_as_int(__expf(lrelu(a.y + dd.y)));
    stnt(erec, (unsigned)pos * 16u, rec);
  }
}

// ---------- MFMA matmul layer2 body (OC=64, bf16 X) — no alpha; hb read-once -> nontemporal ----------
static __device__ __forceinline__ void mmt2_body(int bid, const unsigned short* __restrict__ Xb,
                                                 const unsigned short* __restrict__ Wb,
                                                 unsigned short* __restrict__ outb){
  constexpr int OC = 64, CT = 4;
  int t = threadIdx.x;
  int w = t >> 6, L = t & 63;
  int col = L & 15, quad = L >> 4;
  int row0 = bid*64 + w*16;
  int rA = row0 + col;
  if(rA >= N_NODES) rA = N_NODES-1;

  f32x4 acc[CT];
  #pragma unroll
  for(int ct=0;ct<CT;ct++) acc[ct] = (f32x4){0.f,0.f,0.f,0.f};

  #pragma unroll
  for(int kc=0;kc<4;kc++){
    int k0 = kc*32 + quad*8;
    bf16x8 a = __builtin_nontemporal_load((const bf16x8*)(Xb + (size_t)rA*KD + k0));
    #pragma unroll
    for(int ct=0;ct<CT;ct++){
      bf16x8 b = *(const bf16x8*)(Wb + (size_t)(ct*16 + col)*KD + k0);
      acc[ct] = __builtin_amdgcn_mfma_f32_16x16x32_bf16(a, b, acc[ct], 0, 0, 0);
    }
  }

  #pragma unroll
  for(int r=0;r<4;r++){
    int row = row0 + quad*4 + r;
    #pragma unroll
    for(int ct=0;ct<CT;ct++)
      if(row < N_NODES) outb[(size_t)row*OC + ct*16 + col] = f2bf(acc[ct][r]);
  }
}

// ---------- edge-parallel softmax-weight body: rewrite w fields of erec (nt 16B r/w) ----------
static __device__ __forceinline__ void wcalc_body(int bid, int4* __restrict__ erec,
                                                  const float* __restrict__ as, const float* __restrict__ ad){
  int i = bid*256 + threadIdx.x;
  if(i >= ET) return;
  i32x4 r = ldnt(erec, (unsigned)i * 16u);
  float2 a = ((const float2*)as)[r[0]];
  float2 b = ((const float2*)ad)[r[1]];
  r[2] = __float_as_int(__expf(lrelu(a.x + b.x)));
  r[3] = __float_as_int(__expf(lrelu(a.y + b.y)));
  stnt(erec, (unsigned)i * 16u, r);
}

// packC: mmt2 (782) || wcalc2 (3321) — independent after agg1
__global__ __launch_bounds__(256) void packC_kernel(const unsigned short* __restrict__ Xb,
                                                    const unsigned short* __restrict__ Wb,
                                                    unsigned short* __restrict__ outb,
                                                    int4* __restrict__ erec,
                                                    const float* __restrict__ as2, const float* __restrict__ ad2){
  if(blockIdx.x < MM2B) mmt2_body(blockIdx.x, Xb, Wb, outb);
  else                  wcalc_body(blockIdx.x - MM2B, erec, as2, ad2);
}

// ---------- agg layer 1: 8 edges/iter (R8 structure), nt record loads + cached uint4 gathers + fused alpha2 ----------
__global__ __launch_bounds__(256) void agg1_kernel(const int* __restrict__ rowptr, const int4* __restrict__ erec,
                                                   const uint4* __restrict__ xb4,
                                                   const float* __restrict__ b1, uint4* __restrict__ hb4,
                                                   const float* __restrict__ va,
                                                   float* __restrict__ as2, float* __restrict__ ad2){
  int node = blockIdx.x*4 + (threadIdx.x>>6);
  int l = threadIdx.x & 63;
  if(node >= N_NODES) return;
  int g = l >> 4, c = l & 15;
  unsigned csh = (unsigned)c << 4;
  int beg = rowptr[node], end = rowptr[node+1];
  int n = end - beg;
  float a0=0.f,a1=0.f,a2=0.f,a3=0.f,a4=0.f,a5=0.f,a6=0.f,a7=0.f;
  float s0=0.f, s1=0.f;

#define S1_STEP(IDX) { \
    i32x4 r_ = ldnt(erec, (unsigned)(IDX) * 16u); \
    float wx_ = __int_as_float(r_[2]), wy_ = __int_as_float(r_[3]); \
    uint4 u_ = ld16u(xb4, ((unsigned)r_[0] << 8) | csh); \
    s0 += wx_; s1 += wy_; \
    float vv = (c < 8) ? wx_ : wy_; \
    a0 += vv*lof(u_.x); a1 += vv*hif(u_.x); \
    a2 += vv*lof(u_.y); a3 += vv*hif(u_.y); \
    a4 += vv*lof(u_.z); a5 += vv*hif(u_.z); \
    a6 += vv*lof(u_.w); a7 += vv*hif(u_.w); }

#define S1_STEPM(IDX) { \
    i32x4 r_ = ldnt(erec, (unsigned)(IDX) * 16u); \
    uint4 u_ = ld16u(xb4, ((unsigned)r_[0] << 8) | csh); \
    float wx_ = ((IDX) < end) ? __int_as_float(r_[2]) : 0.f; \
    float wy_ = ((IDX) < end) ? __int_as_float(r_[3]) : 0.f; \
    s0 += wx_; s1 += wy_; \
    float vv = (c < 8) ? wx_ : wy_; \
    a0 += vv*lof(u_.x); a1 += vv*hif(u_.x); \
    a2 += vv*lof(u_.y); a3 += vv*hif(u_.y); \
    a4 += vv*lof(u_.z); a5 += vv*hif(u_.z); \
    a6 += vv*lof(u_.w); a7 += vv*hif(u_.w); }

  int i = beg;
  int nfull = n & ~7;
  for(; i < beg + nfull; i += 8){
    S1_STEP(i + g)
    S1_STEP(i + 4 + g)
  }
  if(i < end){               // masked epilogue: pad gathers hit row 0 (L1-hot)
    S1_STEPM(i + g)
    S1_STEPM(i + 4 + g)
  }
#undef S1_STEP
#undef S1_STEPM

  #pragma unroll
  for(int off=16; off<64; off<<=1){
    s0 += __shfl_xor(s0,off); s1 += __shfl_xor(s1,off);
    a0 += __shfl_xor(a0,off); a1 += __shfl_xor(a1,off);
    a2 += __shfl_xor(a2,off); a3 += __shfl_xor(a3,off);
    a4 += __shfl_xor(a4,off); a5 += __shfl_xor(a5,off);
    a6 += __shfl_xor(a6,off); a7 += __shfl_xor(a7,off);
  }
  float sd = (c < 8) ? s0 : s1;
  float inv = 1.f / sd;
  const float4* bp = (const float4*)(b1 + 8*c);
  float4 bl = bp[0], bh = bp[1];
  float r0 = fmaxf(a0*inv + bl.x, 0.f);
  float r1 = fmaxf(a1*inv + bl.y, 0.f);
  float r2 = fmaxf(a2*inv + bl.z, 0.f);
  float r3 = fmaxf(a3*inv + bl.w, 0.f);
  float r4 = fmaxf(a4*inv + bh.x, 0.f);
  float r5 = fmaxf(a5*inv + bh.y, 0.f);
  float r6 = fmaxf(a6*inv + bh.z, 0.f);
  float r7 = fmaxf(a7*inv + bh.w, 0.f);
  if(g == 0){
    i32x4 o;
    o[0] = (int)pack2(r0, r1); o[1] = (int)pack2(r2, r3);
    o[2] = (int)pack2(r4, r5); o[3] = (int)pack2(r6, r7);
    stnt(hb4, ((unsigned)node << 8) | csh, o);   // write-once stream
  }
  // ---- fused alpha2: p = h . va (4 vectors), reduce over 16 c-lanes ----
  const float4* v0 = (const float4*)(va +        8*c);   // src-mu
  const float4* v1 = (const float4*)(va + 128 +  8*c);   // dst-mu
  const float4* v2 = (const float4*)(va + 256 +  8*c);   // src-std
  const float4* v3 = (const float4*)(va + 384 +  8*c);   // dst-std
  float4 m0 = v0[0], m1 = v0[1], d0v = v1[0], d1v = v1[1];
  float4 t0 = v2[0], t1 = v2[1], u0 = v3[0], u1 = v3[1];
  float psmu = r0*m0.x + r1*m0.y + r2*m0.z + r3*m0.w + r4*m1.x + r5*m1.y + r6*m1.z + r7*m1.w;
  float pdmu = r0*d0v.x + r1*d0v.y + r2*d0v.z + r3*d0v.w + r4*d1v.x + r5*d1v.y + r6*d1v.z + r7*d1v.w;
  float psst = r0*t0.x + r1*t0.y + r2*t0.z + r3*t0.w + r4*t1.x + r5*t1.y + r6*t1.z + r7*t1.w;
  float pdst = r0*u0.x + r1*u0.y + r2*u0.z + r3*u0.w + r4*u1.x + r5*u1.y + r6*u1.z + r7*u1.w;
  #pragma unroll
  for(int off=1; off<16; off<<=1){
    psmu += __shfl_xor(psmu, off); pdmu += __shfl_xor(pdmu, off);
    psst += __shfl_xor(psst, off); pdst += __shfl_xor(pdst, off);
  }
  if(l == 0){
    as2[node*2] = psmu; as2[node*2+1] = psst;
    ad2[node*2] = pdmu; ad2[node*2+1] = pdst;
  }
}

// ---------- agg layer 2: 8 edges/step, nt record loads + cached uint4 row gathers ----------
__global__ __launch_bounds__(256) void agg2_kernel(const int* __restrict__ rowptr, const int4* __restrict__ erec,
                                                   const uint4* __restrict__ xb4,
                                                   const float* __restrict__ bmu, const float* __restrict__ bst,
                                                   float* __restrict__ out){
  int node = blockIdx.x*4 + (threadIdx.x>>6);
  int l = threadIdx.x & 63;
  if(node >= N_NODES) return;
  int g = l >> 3, c = l & 7;
  unsigned csh = (unsigned)c << 4;
  int beg = rowptr[node], end = rowptr[node+1];
  int n = end - beg;
  float a0=0.f,a1=0.f,a2=0.f,a3=0.f,a4=0.f,a5=0.f,a6=0.f,a7=0.f;
  float smu=0.f, sst=0.f;

#define S2_STEP(IDX) { \
    i32x4 r_ = ldnt(erec, (unsigned)(IDX) * 16u); \
    float wx_ = __int_as_float(r_[2]), wy_ = __int_as_float(r_[3]); \
    uint4 u_ = ld16u(xb4, ((unsigned)r_[0] << 7) | csh); \
    smu += wx_; sst += wy_; \
    float vv = (c < 4) ? wx_ : wy_; \
    a0 += vv*lof(u_.x); a1 += vv*hif(u_.x); \
    a2 += vv*lof(u_.y); a3 += vv*hif(u_.y); \
    a4 += vv*lof(u_.z); a5 += vv*hif(u_.z); \
    a6 += vv*lof(u_.w); a7 += vv*hif(u_.w); }

#define S2_STEPM(IDX) { \
    i32x4 r_ = ldnt(erec, (unsigned)(IDX) * 16u); \
    uint4 u_ = ld16u(xb4, ((unsigned)r_[0] << 7) | csh); \
    float wx_ = ((IDX) < end) ? __int_as_float(r_[2]) : 0.f; \
    float wy_ = ((IDX) < end) ? __int_as_float(r_[3]) : 0.f; \
    smu += wx_; sst += wy_; \
    float vv = (c < 4) ? wx_ : wy_; \
    a0 += vv*lof(u_.x); a1 += vv*hif(u_.x); \
    a2 += vv*lof(u_.y); a3 += vv*hif(u_.y); \
    a4 += vv*lof(u_.z); a5 += vv*hif(u_.z); \
    a6 += vv*lof(u_.w); a7 += vv*hif(u_.w); }

  int i = beg;
  int nfull = n & ~15;
  for(; i < beg + nfull; i += 16){
    S2_STEP(i + g)
    S2_STEP(i + 8 + g)
  }
  if(i < end){               // masked epilogue
    S2_STEPM(i + g)
    S2_STEPM(i + 8 + g)
  }
#undef S2_STEP
#undef S2_STEPM

  #pragma unroll
  for(int off=8; off<64; off<<=1){
    smu += __shfl_xor(smu,off); sst += __shfl_xor(sst,off);
    a0 += __shfl_xor(a0,off); a1 += __shfl_xor(a1,off);
    a2 += __shfl_xor(a2,off); a3 += __shfl_xor(a3,off);
    a4 += __shfl_xor(a4,off); a5 += __shfl_xor(a5,off);
    a6 += __shfl_xor(a6,off); a7 += __shfl_xor(a7,off);
  }
  if(g == 0){
    float sd = (c < 4) ? smu : sst;
    float inv = 1.f / sd;
    const float* bb = (c < 4) ? (bmu + 8*c) : (bst + 8*(c-4));
    float4 bl = *(const float4*)bb;
    float4 bh = *(const float4*)(bb + 4);
    float* op = (c < 4) ? (out + (size_t)node*Z + 8*c)
                        : (out + (size_t)N_NODES*Z + (size_t)node*Z + 8*(c-4));
    float4 r0, r1;
    r0.x = a0*inv + bl.x; r0.y = a1*inv + bl.y;
    r0.z = a2*inv + bl.z; r0.w = a3*inv + bl.w;
    r1.x = a4*inv + bh.x; r1.y = a5*inv + bh.y;
    r1.z = a6*inv + bh.z; r1.w = a7*inv + bh.w;
    *(float4*)op = r0;
    *((float4*)op + 1) = r1;
  }
}

extern "C" void kernel_launch(void* const* d_in, const int* in_sizes, int n_in,
                              void* d_out, int out_size, void* d_ws, size_t ws_size,
                              hipStream_t stream){
  const float* x    = (const float*)d_in[0];
  const int*   edges= (const int*)d_in[1];
  const float* W1   = (const float*)d_in[2];
  const float* as1v = (const float*)d_in[3];
  const float* ad1v = (const float*)d_in[4];
  const float* b1   = (const float*)d_in[5];
  const float* Wmu  = (const float*)d_in[6];
  const float* asmu = (const float*)d_in[7];
  const float* admu = (const float*)d_in[8];
  const float* bmu  = (const float*)d_in[9];
  const float* Wst  = (const float*)d_in[10];
  const float* asst = (const float*)d_in[11];
  const float* adst = (const float*)d_in[12];
  const float* bst  = (const float*)d_in[13];
  float* out = (float*)d_out;

  char* p = (char*)d_ws;
  auto alloc = [&](size_t bytes)->char*{ char* r = p; p += (bytes + 255) & ~size_t(255); return r; };
  int*   M      = (int*)  alloc((size_t)MTOT*4);
  int*   Mpos   = (int*)  alloc((size_t)MTOT*4);
  int*   bsumM  = (int*)  alloc((size_t)MBS*4);
  unsigned int* etmp = (unsigned int*)alloc((size_t)ET*4);   // packed src|lo7<<17
  int4*  erec   = (int4*) alloc((size_t)(ET+32)*16);         // {src,dst,wx,wy}; +32 zeroed pad
  int*   rowptr = (int*)  alloc((size_t)(N_NODES+1)*4);
  float* va     = (float*)alloc((size_t)512*4);
  unsigned short* Wb1 = (unsigned short*)alloc((size_t)128*KD*2);
  unsigned short* Wb2 = (unsigned short*)alloc((size_t)64*KD*2);
  unsigned short* xpb1 = (unsigned short*)alloc((size_t)N_NODES*128*2);
  float* as1    = (float*)alloc((size_t)N_NODES*2*4);
  float* ad1    = (float*)alloc((size_t)N_NODES*2*4);
  unsigned short* hb = (unsigned short*)alloc((size_t)N_NODES*128*2);
  float* as2    = (float*)alloc((size_t)N_NODES*2*4);
  float* ad2    = (float*)alloc((size_t)N_NODES*2*4);
  unsigned short* xpb2 = xpb1;                          // xpb1 dead after agg1

  packA_kernel  <<<NBLKA + WCB + 1, 256, 0, stream>>>(edges, M, W1, Wmu, Wst, Wb1, Wb2, erec,
                                                      asmu, admu, asst, adst, va);
  scanM1_kernel <<<MBS, 256, 0, stream>>>(M, bsumM);
  scanM23_kernel<<<MBS, 256, 0, stream>>>(M, bsumM, Mpos);
  packB_kernel  <<<NBLKA + MM2B, 256, 0, stream>>>(edges, Mpos, etmp,
                                                   x, Wb1, as1v, ad1v, xpb1, as1, ad1);
  bfin_kernel   <<<NBUCK, 256, 0, stream>>>(Mpos, etmp, rowptr, erec, as1, ad1);

  agg1_kernel  <<<(N_NODES+3)/4, 256, 0, stream>>>(rowptr, erec, (const uint4*)xpb1, b1, (uint4*)hb,
                                                   va, as2, ad2);
  packC_kernel <<<MM2B + WCE, 256, 0, stream>>>(hb, Wb2, xpb1, erec, as2, ad2);
  agg2_kernel  <<<(N_NODES+3)/4, 256, 0, stream>>>(rowptr, erec, (const uint4*)xpb2, bmu, bst, out);
}

// Round 11
// 221.976 us; speedup vs baseline: 1.1298x; 1.1298x over previous
//
#include <hip/hip_runtime.h>
#include <math.h>

#define N_NODES 50000
#define N_EDGES 800000
#define ET (N_EDGES + N_NODES)   // 850000 incl. self-loops
#define KD 128
#define Z 32
#define SH 7
#define BW 128                              // nodes per bucket
#define NBUCK ((N_NODES + BW - 1) / BW)     // 391
#define CHUNK 4096
#define NBLKA ((ET + CHUNK - 1) / CHUNK)    // 208 chunks
#define MTOT (NBUCK * NBLKA)                // 81,328
#define MBS ((MTOT + 1023) / 1024)          // 80
#define WCB 64                              // wconv blocks
#define MM2B ((N_NODES + 63) / 64)          // 782 mmt2 blocks
#define WCE ((ET + 255) / 256)              // 3321 wcalc blocks

typedef __attribute__((ext_vector_type(8))) short bf16x8;
typedef __attribute__((ext_vector_type(4))) float f32x4;

static __device__ __forceinline__ float lrelu(float x){ return x > 0.f ? x : 0.2f*x; }
static __device__ __forceinline__ float lof(unsigned int u){ return __uint_as_float(u << 16); }
static __device__ __forceinline__ float hif(unsigned int u){ return __uint_as_float(u & 0xffff0000u); }
static __device__ __forceinline__ unsigned short f2bf(float f){
  unsigned int x = __float_as_uint(f);
  return (unsigned short)((x + 0x7fffu + ((x >> 16) & 1u)) >> 16);   // RNE
}
static __device__ __forceinline__ unsigned int pack2(float lo, float hi){
  return (unsigned int)f2bf(lo) | ((unsigned int)f2bf(hi) << 16);
}
// saddr-form loads/stores: base(SGPR) + unsigned byte offset (32-bit VGPR)
static __device__ __forceinline__ int4 ld16i(const void* base, unsigned boff){
  return *(const int4*)((const char*)base + boff);
}
static __device__ __forceinline__ uint4 ld16u(const void* base, unsigned boff){
  return *(const uint4*)((const char*)base + boff);
}
static __device__ __forceinline__ void st16i(void* base, unsigned boff, int4 v){
  *(int4*)((char*)base + boff) = v;
}

// ---------- bodies for packed kernels ----------
static __device__ __forceinline__ void bhistA_body(int k, const int* __restrict__ edges, int* __restrict__ M){
  int t = threadIdx.x;
  __shared__ int cnt[NBUCK];
  for(int b = t; b < NBUCK; b += 256) cnt[b] = 0;
  __syncthreads();
  int base = k*CHUNK;
  int lim = min(base + CHUNK, ET);
  for(int i = base + t; i < lim; i += 256){
    int d = (i < N_EDGES) ? edges[N_EDGES + i] : (i - N_EDGES);
    atomicAdd(&cnt[d >> SH], 1);
  }
  __syncthreads();
  for(int b = t; b < NBUCK; b += 256) M[b*NBLKA + k] = cnt[b];
}

static __device__ __forceinline__ void wconv_body(int bid, const float* __restrict__ W1,
                                                  const float* __restrict__ Wmu, const float* __restrict__ Wst,
                                                  unsigned short* __restrict__ Wb1, unsigned short* __restrict__ Wb2,
                                                  int4* __restrict__ erec){
  int i = bid*256 + threadIdx.x;
  if(i < 128*KD) Wb1[i] = f2bf(W1[i]);
  if(i < 64*KD) Wb2[i] = f2bf(i < 32*KD ? Wmu[i] : Wst[i - 32*KD]);
  if(i < 32) erec[ET + i] = make_int4(0,0,0,0);   // zero pad: agg kernels overread up to +16
}

// va[k] = sum_z a[z] * W[z*128+k]  (alpha-2 folded vectors: (h W^T) a == h (W^T a))
static __device__ __forceinline__ void vacalc_body(const float* __restrict__ Wmu, const float* __restrict__ Wst,
                                                   const float* __restrict__ asmu, const float* __restrict__ admu,
                                                   const float* __restrict__ asst, const float* __restrict__ adst,
                                                   float* __restrict__ va){
  int k = threadIdx.x;
  if(k >= 128) return;
  float smu = 0.f, dmu = 0.f, sst = 0.f, dst = 0.f;
  #pragma unroll 8
  for(int z = 0; z < Z; z++){
    float wm = Wmu[z*128 + k], ws = Wst[z*128 + k];
    smu += asmu[z]*wm; dmu += admu[z]*wm;
    sst += asst[z]*ws; dst += adst[z]*ws;
  }
  va[k] = smu; va[128 + k] = dmu; va[256 + k] = sst; va[384 + k] = dst;
}

// packA: bhistA (208) || wconv (64) || vacalc (1)
__global__ __launch_bounds__(256) void packA_kernel(const int* __restrict__ edges, int* __restrict__ M,
                                                    const float* __restrict__ W1,
                                                    const float* __restrict__ Wmu, const float* __restrict__ Wst,
                                                    unsigned short* __restrict__ Wb1, unsigned short* __restrict__ Wb2,
                                                    int4* __restrict__ erec,
                                                    const float* __restrict__ asmu, const float* __restrict__ admu,
                                                    const float* __restrict__ asst, const float* __restrict__ adst,
                                                    float* __restrict__ va){
  if(blockIdx.x < NBLKA)            bhistA_body(blockIdx.x, edges, M);
  else if(blockIdx.x < NBLKA + WCB) wconv_body(blockIdx.x - NBLKA, W1, Wmu, Wst, Wb1, Wb2, erec);
  else                              vacalc_body(Wmu, Wst, asmu, admu, asst, adst, va);
}

__global__ __launch_bounds__(256) void scanM1_kernel(const int* __restrict__ M, int* __restrict__ bsumM){
  int b = blockIdx.x, t = threadIdx.x;
  int base = b*1024 + t*4;
  int s = 0;
  #pragma unroll
  for(int i=0;i<4;i++){ int n = base+i; if(n < MTOT) s += M[n]; }
  for(int off=32; off; off>>=1) s += __shfl_xor(s, off);
  __shared__ int ws[4];
  if((t&63)==0) ws[t>>6] = s;
  __syncthreads();
  if(t==0) bsumM[b] = ws[0]+ws[1]+ws[2]+ws[3];
}

// scanM3 with scanM2 folded in: each block computes its own bsumM prefix
__global__ __launch_bounds__(256) void scanM23_kernel(const int* __restrict__ M, const int* __restrict__ bsumM,
                                                      int* __restrict__ Mpos){
  int b = blockIdx.x, t = threadIdx.x;
  int lane = t & 63, wv = t >> 6;
  __shared__ int wsum[4];
  int pv = (t < b && t < MBS) ? bsumM[t] : 0;
  for(int off=32; off; off>>=1) pv += __shfl_xor(pv, off);
  if(lane == 0) wsum[wv] = pv;
  __syncthreads();
  int bpre = wsum[0] + wsum[1] + wsum[2] + wsum[3];
  int base = b*1024 + t*4;
  int d[4]; int s = 0;
  #pragma unroll
  for(int i=0;i<4;i++){ int n = base+i; d[i] = (n < MTOT) ? M[n] : 0; s += d[i]; }
  int v = s;
  for(int off=1; off<64; off<<=1){
    int u = __shfl_up(v, off);
    if(lane >= off) v += u;
  }
  int texcl = v - s;
  __shared__ int wtot[4];
  if(lane == 63) wtot[wv] = v;
  __syncthreads();
  int woff = 0;
  for(int i=0;i<wv;i++) woff += wtot[i];
  int run = bpre + woff + texcl;
  #pragma unroll
  for(int i=0;i<4;i++){
    int n = base+i;
    if(n < MTOT){ Mpos[n] = run; run += d[i]; }
  }
}

// bplaceA body: etmp entry packed as src(17b) | lo7(d)<<17
static __device__ __forceinline__ void bplaceA_body(int k, const int* __restrict__ edges,
                                                    const int* __restrict__ Mpos, unsigned int* __restrict__ etmp){
  int t = threadIdx.x;
  __shared__ int cur[NBUCK];
  for(int b = t; b < NBUCK; b += 256) cur[b] = Mpos[b*NBLKA + k];
  __syncthreads();
  int base = k*CHUNK;
  int lim = min(base + CHUNK, ET);
  for(int i = base + t; i < lim; i += 256){
    int s, d;
    if(i < N_EDGES){ s = edges[i]; d = edges[N_EDGES+i]; } else { s = d = i - N_EDGES; }
    int pos = atomicAdd(&cur[d >> SH], 1);
    etmp[pos] = (unsigned int)s | ((unsigned int)(d & (BW-1)) << 17);
  }
}

// ---------- MFMA matmul layer1 body (OC=128) + fused alpha1 ----------
static __device__ __forceinline__ void mmt1_body(int bid, const float* __restrict__ X,
                                                 const unsigned short* __restrict__ Wb,
                                                 const float* __restrict__ asv, const float* __restrict__ adv,
                                                 unsigned short* __restrict__ outb,
                                                 float* __restrict__ as1, float* __restrict__ ad1){
  constexpr int OC = 128, CT = 8;
  int t = threadIdx.x;
  int w = t >> 6, L = t & 63;
  int col = L & 15, quad = L >> 4;
  int row0 = bid*64 + w*16;
  int rA = row0 + col;
  if(rA >= N_NODES) rA = N_NODES-1;

  f32x4 acc[CT];
  #pragma unroll
  for(int ct=0;ct<CT;ct++) acc[ct] = (f32x4){0.f,0.f,0.f,0.f};

  #pragma unroll
  for(int kc=0;kc<4;kc++){
    int k0 = kc*32 + quad*8;
    const float* Xf = X + (size_t)rA*KD + k0;
    float4 p = *(const float4*)Xf;
    float4 q = *(const float4*)(Xf + 4);
    bf16x8 a;
    a[0] = (short)f2bf(p.x); a[1] = (short)f2bf(p.y);
    a[2] = (short)f2bf(p.z); a[3] = (short)f2bf(p.w);
    a[4] = (short)f2bf(q.x); a[5] = (short)f2bf(q.y);
    a[6] = (short)f2bf(q.z); a[7] = (short)f2bf(q.w);
    #pragma unroll
    for(int ct=0;ct<CT;ct++){
      bf16x8 b = *(const bf16x8*)(Wb + (size_t)(ct*16 + col)*KD + k0);
      acc[ct] = __builtin_amdgcn_mfma_f32_16x16x32_bf16(a, b, acc[ct], 0, 0, 0);
    }
  }

  float av[CT], dv[CT];
  #pragma unroll
  for(int ct=0;ct<CT;ct++){ av[ct] = asv[ct*16 + col]; dv[ct] = adv[ct*16 + col]; }

  #pragma unroll
  for(int r=0;r<4;r++){
    int row = row0 + quad*4 + r;
    #pragma unroll
    for(int ct=0;ct<CT;ct++)
      if(row < N_NODES) outb[(size_t)row*OC + ct*16 + col] = f2bf(acc[ct][r]);
    float s0 = acc[0][r]*av[0] + acc[1][r]*av[1] + acc[2][r]*av[2] + acc[3][r]*av[3];
    float s1 = acc[4][r]*av[4] + acc[5][r]*av[5] + acc[6][r]*av[6] + acc[7][r]*av[7];
    float d0 = acc[0][r]*dv[0] + acc[1][r]*dv[1] + acc[2][r]*dv[2] + acc[3][r]*dv[3];
    float d1 = acc[4][r]*dv[4] + acc[5][r]*dv[5] + acc[6][r]*dv[6] + acc[7][r]*dv[7];
    #pragma unroll
    for(int off=1; off<16; off<<=1){
      s0 += __shfl_xor(s0, off); s1 += __shfl_xor(s1, off);
      d0 += __shfl_xor(d0, off); d1 += __shfl_xor(d1, off);
    }
    if(col == 0 && row < N_NODES){
      as1[row*2] = s0; as1[row*2+1] = s1;
      ad1[row*2] = d0; ad1[row*2+1] = d1;
    }
  }
}

// packB: bplaceA (208) || mmt1 (782)
__global__ __launch_bounds__(256) void packB_kernel(const int* __restrict__ edges, const int* __restrict__ Mpos,
                                                    unsigned int* __restrict__ etmp,
                                                    const float* __restrict__ X, const unsigned short* __restrict__ Wb,
                                                    const float* __restrict__ asv, const float* __restrict__ adv,
                                                    unsigned short* __restrict__ outb,
                                                    float* __restrict__ as1, float* __restrict__ ad1){
  if(blockIdx.x < NBLKA) bplaceA_body(blockIdx.x, edges, Mpos, etmp);
  else                   mmt1_body(blockIdx.x - NBLKA, X, Wb, asv, adv, outb, as1, ad1);
}

// fused: bucket histogram + scan -> rowptr + place -> erec {src,dst,w1x,w1y} (wcalc1 fused)
__global__ __launch_bounds__(256) void bfin_kernel(const int* __restrict__ Mpos, const unsigned int* __restrict__ etmp,
                                                   int* __restrict__ rowptr, int4* __restrict__ erec,
                                                   const float* __restrict__ as1, const float* __restrict__ ad1){
  int b = blockIdx.x, t = threadIdx.x;
  __shared__ int cnt[BW];
  __shared__ int pre[BW];
  __shared__ int lcur[BW];
  __shared__ float2 adl[BW];
  if(t < BW){
    cnt[t] = 0;
    int node = b*BW + t;
    adl[t] = (node < N_NODES) ? ((const float2*)ad1)[node] : make_float2(0.f, 0.f);
  }
  __syncthreads();
  int beg = Mpos[b*NBLKA];
  int end = (b+1 < NBUCK) ? Mpos[(b+1)*NBLKA] : ET;
  for(int i = beg + t; i < end; i += 256) atomicAdd(&cnt[etmp[i] >> 17], 1);
  __syncthreads();
  if(t < BW) pre[t] = cnt[t];
  __syncthreads();
  for(int off=1; off<BW; off<<=1){
    int u = 0;
    if(t < BW && t >= off) u = pre[t-off];
    __syncthreads();
    if(t < BW) pre[t] += u;
    __syncthreads();
  }
  if(t < BW){
    int excl = pre[t] - cnt[t];
    int node = b*BW + t;
    if(node < N_NODES) rowptr[node] = beg + excl;
    lcur[t] = beg + excl;
  }
  if(b == 0 && t == 255) rowptr[N_NODES] = ET;
  __syncthreads();
  const float2* asp = (const float2*)as1;
  for(int i = beg + t; i < end; i += 256){
    unsigned int e = etmp[i];
    int lo = (int)(e >> 17);
    int s  = (int)(e & 0x1FFFFu);
    int pos = atomicAdd(&lcur[lo], 1);
    float2 a = asp[s];
    float2 dd = adl[lo];
    int4 rec;
    rec.x = s;
    rec.y = b*BW + lo;
    rec.z = __float_as_int(__expf(lrelu(a.x + dd.x)));
    rec.w = __float_as_int(__expf(lrelu(a.y + dd.y)));
    st16i(erec, (unsigned)pos * 16u, rec);
  }
}

// ---------- MFMA matmul layer2 body (OC=64, bf16 X) — no alpha (moved to agg1) ----------
static __device__ __forceinline__ void mmt2_body(int bid, const unsigned short* __restrict__ Xb,
                                                 const unsigned short* __restrict__ Wb,
                                                 unsigned short* __restrict__ outb){
  constexpr int OC = 64, CT = 4;
  int t = threadIdx.x;
  int w = t >> 6, L = t & 63;
  int col = L & 15, quad = L >> 4;
  int row0 = bid*64 + w*16;
  int rA = row0 + col;
  if(rA >= N_NODES) rA = N_NODES-1;

  f32x4 acc[CT];
  #pragma unroll
  for(int ct=0;ct<CT;ct++) acc[ct] = (f32x4){0.f,0.f,0.f,0.f};

  #pragma unroll
  for(int kc=0;kc<4;kc++){
    int k0 = kc*32 + quad*8;
    bf16x8 a = *(const bf16x8*)(Xb + (size_t)rA*KD + k0);
    #pragma unroll
    for(int ct=0;ct<CT;ct++){
      bf16x8 b = *(const bf16x8*)(Wb + (size_t)(ct*16 + col)*KD + k0);
      acc[ct] = __builtin_amdgcn_mfma_f32_16x16x32_bf16(a, b, acc[ct], 0, 0, 0);
    }
  }

  #pragma unroll
  for(int r=0;r<4;r++){
    int row = row0 + quad*4 + r;
    #pragma unroll
    for(int ct=0;ct<CT;ct++)
      if(row < N_NODES) outb[(size_t)row*OC + ct*16 + col] = f2bf(acc[ct][r]);
  }
}

// ---------- edge-parallel softmax-weight body: rewrite w fields of erec (coalesced 16B r/w) ----------
static __device__ __forceinline__ void wcalc_body(int bid, int4* __restrict__ erec,
                                                  const float* __restrict__ as, const float* __restrict__ ad){
  int i = bid*256 + threadIdx.x;
  if(i >= ET) return;
  int4 r = ld16i(erec, (unsigned)i * 16u);
  float2 a = ((const float2*)as)[r.x];
  float2 b = ((const float2*)ad)[r.y];
  r.z = __float_as_int(__expf(lrelu(a.x + b.x)));
  r.w = __float_as_int(__expf(lrelu(a.y + b.y)));
  st16i(erec, (unsigned)i * 16u, r);
}

// packC: mmt2 (782) || wcalc2 (3321) — independent after agg1
__global__ __launch_bounds__(256) void packC_kernel(const unsigned short* __restrict__ Xb,
                                                    const unsigned short* __restrict__ Wb,
                                                    unsigned short* __restrict__ outb,
                                                    int4* __restrict__ erec,
                                                    const float* __restrict__ as2, const float* __restrict__ ad2){
  if(blockIdx.x < MM2B) mmt2_body(blockIdx.x, Xb, Wb, outb);
  else                  wcalc_body(blockIdx.x - MM2B, erec, as2, ad2);
}

// ---------- agg layer 1: 8 edges/iter, record loads + uint4 row gathers + fused alpha2 ----------
__global__ __launch_bounds__(256) void agg1_kernel(const int* __restrict__ rowptr, const int4* __restrict__ erec,
                                                   const uint4* __restrict__ xb4,
                                                   const float* __restrict__ b1, uint4* __restrict__ hb4,
                                                   const float* __restrict__ va,
                                                   float* __restrict__ as2, float* __restrict__ ad2){
  int node = blockIdx.x*4 + (threadIdx.x>>6);
  int l = threadIdx.x & 63;
  if(node >= N_NODES) return;
  int g = l >> 4, c = l & 15;
  unsigned csh = (unsigned)c << 4;
  int beg = rowptr[node], end = rowptr[node+1];
  int n = end - beg;
  float a0=0.f,a1=0.f,a2=0.f,a3=0.f,a4=0.f,a5=0.f,a6=0.f,a7=0.f;
  float s0=0.f, s1=0.f;

#define S1_STEP(IDX) { \
    int4 r_ = ld16i(erec, (unsigned)(IDX) * 16u); \
    float wx_ = __int_as_float(r_.z), wy_ = __int_as_float(r_.w); \
    uint4 u_ = ld16u(xb4, ((unsigned)r_.x << 8) | csh); \
    s0 += wx_; s1 += wy_; \
    float vv = (c < 8) ? wx_ : wy_; \
    a0 += vv*lof(u_.x); a1 += vv*hif(u_.x); \
    a2 += vv*lof(u_.y); a3 += vv*hif(u_.y); \
    a4 += vv*lof(u_.z); a5 += vv*hif(u_.z); \
    a6 += vv*lof(u_.w); a7 += vv*hif(u_.w); }

#define S1_STEPM(IDX) { \
    int4 r_ = ld16i(erec, (unsigned)(IDX) * 16u); \
    uint4 u_ = ld16u(xb4, ((unsigned)r_.x << 8) | csh); \
    float wx_ = ((IDX) < end) ? __int_as_float(r_.z) : 0.f; \
    float wy_ = ((IDX) < end) ? __int_as_float(r_.w) : 0.f; \
    s0 += wx_; s1 += wy_; \
    float vv = (c < 8) ? wx_ : wy_; \
    a0 += vv*lof(u_.x); a1 += vv*hif(u_.x); \
    a2 += vv*lof(u_.y); a3 += vv*hif(u_.y); \
    a4 += vv*lof(u_.z); a5 += vv*hif(u_.z); \
    a6 += vv*lof(u_.w); a7 += vv*hif(u_.w); }

  int i = beg;
  int nfull = n & ~7;
  for(; i < beg + nfull; i += 8){
    S1_STEP(i + g)
    S1_STEP(i + 4 + g)
  }
  if(i < end){               // masked epilogue: pad gathers hit row 0 (L1-hot)
    S1_STEPM(i + g)
    S1_STEPM(i + 4 + g)
  }
#undef S1_STEP
#undef S1_STEPM

  #pragma unroll
  for(int off=16; off<64; off<<=1){
    s0 += __shfl_xor(s0,off); s1 += __shfl_xor(s1,off);
    a0 += __shfl_xor(a0,off); a1 += __shfl_xor(a1,off);
    a2 += __shfl_xor(a2,off); a3 += __shfl_xor(a3,off);
    a4 += __shfl_xor(a4,off); a5 += __shfl_xor(a5,off);
    a6 += __shfl_xor(a6,off); a7 += __shfl_xor(a7,off);
  }
  float sd = (c < 8) ? s0 : s1;
  float inv = 1.f / sd;
  const float4* bp = (const float4*)(b1 + 8*c);
  float4 bl = bp[0], bh = bp[1];
  float r0 = fmaxf(a0*inv + bl.x, 0.f);
  float r1 = fmaxf(a1*inv + bl.y, 0.f);
  float r2 = fmaxf(a2*inv + bl.z, 0.f);
  float r3 = fmaxf(a3*inv + bl.w, 0.f);
  float r4 = fmaxf(a4*inv + bh.x, 0.f);
  float r5 = fmaxf(a5*inv + bh.y, 0.f);
  float r6 = fmaxf(a6*inv + bh.z, 0.f);
  float r7 = fmaxf(a7*inv + bh.w, 0.f);
  if(g == 0){
    uint4 o;
    o.x = pack2(r0, r1); o.y = pack2(r2, r3);
    o.z = pack2(r4, r5); o.w = pack2(r6, r7);
    hb4[(size_t)node*16 + c] = o;
  }
  // ---- fused alpha2: p = h . va (4 vectors), reduce over 16 c-lanes ----
  const float4* v0 = (const float4*)(va +        8*c);   // src-mu
  const float4* v1 = (const float4*)(va + 128 +  8*c);   // dst-mu
  const float4* v2 = (const float4*)(va + 256 +  8*c);   // src-std
  const float4* v3 = (const float4*)(va + 384 +  8*c);   // dst-std
  float4 m0 = v0[0], m1 = v0[1], d0v = v1[0], d1v = v1[1];
  float4 t0 = v2[0], t1 = v2[1], u0 = v3[0], u1 = v3[1];
  float psmu = r0*m0.x + r1*m0.y + r2*m0.z + r3*m0.w + r4*m1.x + r5*m1.y + r6*m1.z + r7*m1.w;
  float pdmu = r0*d0v.x + r1*d0v.y + r2*d0v.z + r3*d0v.w + r4*d1v.x + r5*d1v.y + r6*d1v.z + r7*d1v.w;
  float psst = r0*t0.x + r1*t0.y + r2*t0.z + r3*t0.w + r4*t1.x + r5*t1.y + r6*t1.z + r7*t1.w;
  float pdst = r0*u0.x + r1*u0.y + r2*u0.z + r3*u0.w + r4*u1.x + r5*u1.y + r6*u1.z + r7*u1.w;
  #pragma unroll
  for(int off=1; off<16; off<<=1){
    psmu += __shfl_xor(psmu, off); pdmu += __shfl_xor(pdmu, off);
    psst += __shfl_xor(psst, off); pdst += __shfl_xor(pdst, off);
  }
  if(l == 0){
    as2[node*2] = psmu; as2[node*2+1] = psst;
    ad2[node*2] = pdmu; ad2[node*2+1] = pdst;
  }
}

// ---------- agg layer 2: 8 edges/step, record loads + uint4 row gathers ----------
__global__ __launch_bounds__(256) void agg2_kernel(const int* __restrict__ rowptr, const int4* __restrict__ erec,
                                                   const uint4* __restrict__ xb4,
                                                   const float* __restrict__ bmu, const float* __restrict__ bst,
                                                   float* __restrict__ out){
  int node = blockIdx.x*4 + (threadIdx.x>>6);
  int l = threadIdx.x & 63;
  if(node >= N_NODES) return;
  int g = l >> 3, c = l & 7;
  unsigned csh = (unsigned)c << 4;
  int beg = rowptr[node], end = rowptr[node+1];
  int n = end - beg;
  float a0=0.f,a1=0.f,a2=0.f,a3=0.f,a4=0.f,a5=0.f,a6=0.f,a7=0.f;
  float smu=0.f, sst=0.f;

#define S2_STEP(IDX) { \
    int4 r_ = ld16i(erec, (unsigned)(IDX) * 16u); \
    float wx_ = __int_as_float(r_.z), wy_ = __int_as_float(r_.w); \
    uint4 u_ = ld16u(xb4, ((unsigned)r_.x << 7) | csh); \
    smu += wx_; sst += wy_; \
    float vv = (c < 4) ? wx_ : wy_; \
    a0 += vv*lof(u_.x); a1 += vv*hif(u_.x); \
    a2 += vv*lof(u_.y); a3 += vv*hif(u_.y); \
    a4 += vv*lof(u_.z); a5 += vv*hif(u_.z); \
    a6 += vv*lof(u_.w); a7 += vv*hif(u_.w); }

#define S2_STEPM(IDX) { \
    int4 r_ = ld16i(erec, (unsigned)(IDX) * 16u); \
    uint4 u_ = ld16u(xb4, ((unsigned)r_.x << 7) | csh); \
    float wx_ = ((IDX) < end) ? __int_as_float(r_.z) : 0.f; \
    float wy_ = ((IDX) < end) ? __int_as_float(r_.w) : 0.f; \
    smu += wx_; sst += wy_; \
    float vv = (c < 4) ? wx_ : wy_; \
    a0 += vv*lof(u_.x); a1 += vv*hif(u_.x); \
    a2 += vv*lof(u_.y); a3 += vv*hif(u_.y); \
    a4 += vv*lof(u_.z); a5 += vv*hif(u_.z); \
    a6 += vv*lof(u_.w); a7 += vv*hif(u_.w); }

  int i = beg;
  int nfull = n & ~15;
  for(; i < beg + nfull; i += 16){
    S2_STEP(i + g)
    S2_STEP(i + 8 + g)
  }
  if(i < end){               // masked epilogue
    S2_STEPM(i + g)
    S2_STEPM(i + 8 + g)
  }
#undef S2_STEP
#undef S2_STEPM

  #pragma unroll
  for(int off=8; off<64; off<<=1){
    smu += __shfl_xor(smu,off); sst += __shfl_xor(sst,off);
    a0 += __shfl_xor(a0,off); a1 += __shfl_xor(a1,off);
    a2 += __shfl_xor(a2,off); a3 += __shfl_xor(a3,off);
    a4 += __shfl_xor(a4,off); a5 += __shfl_xor(a5,off);
    a6 += __shfl_xor(a6,off); a7 += __shfl_xor(a7,off);
  }
  if(g == 0){
    float sd = (c < 4) ? smu : sst;
    float inv = 1.f / sd;
    const float* bb = (c < 4) ? (bmu + 8*c) : (bst + 8*(c-4));
    float4 bl = *(const float4*)bb;
    float4 bh = *(const float4*)(bb + 4);
    float* op = (c < 4) ? (out + (size_t)node*Z + 8*c)
                        : (out + (size_t)N_NODES*Z + (size_t)node*Z + 8*(c-4));
    float4 r0, r1;
    r0.x = a0*inv + bl.x; r0.y = a1*inv + bl.y;
    r0.z = a2*inv + bl.z; r0.w = a3*inv + bl.w;
    r1.x = a4*inv + bh.x; r1.y = a5*inv + bh.y;
    r1.z = a6*inv + bh.z; r1.w = a7*inv + bh.w;
    *(float4*)op = r0;
    *((float4*)op + 1) = r1;
  }
}

extern "C" void kernel_launch(void* const* d_in, const int* in_sizes, int n_in,
                              void* d_out, int out_size, void* d_ws, size_t ws_size,
                              hipStream_t stream){
  const float* x    = (const float*)d_in[0];
  const int*   edges= (const int*)d_in[1];
  const float* W1   = (const float*)d_in[2];
  const float* as1v = (const float*)d_in[3];
  const float* ad1v = (const float*)d_in[4];
  const float* b1   = (const float*)d_in[5];
  const float* Wmu  = (const float*)d_in[6];
  const float* asmu = (const float*)d_in[7];
  const float* admu = (const float*)d_in[8];
  const float* bmu  = (const float*)d_in[9];
  const float* Wst  = (const float*)d_in[10];
  const float* asst = (const float*)d_in[11];
  const float* adst = (const float*)d_in[12];
  const float* bst  = (const float*)d_in[13];
  float* out = (float*)d_out;

  char* p = (char*)d_ws;
  auto alloc = [&](size_t bytes)->char*{ char* r = p; p += (bytes + 255) & ~size_t(255); return r; };
  int*   M      = (int*)  alloc((size_t)MTOT*4);
  int*   Mpos   = (int*)  alloc((size_t)MTOT*4);
  int*   bsumM  = (int*)  alloc((size_t)MBS*4);
  unsigned int* etmp = (unsigned int*)alloc((size_t)ET*4);   // packed src|lo7<<17
  int4*  erec   = (int4*) alloc((size_t)(ET+32)*16);         // {src,dst,wx,wy}; +32 zeroed pad
  int*   rowptr = (int*)  alloc((size_t)(N_NODES+1)*4);
  float* va     = (float*)alloc((size_t)512*4);
  unsigned short* Wb1 = (unsigned short*)alloc((size_t)128*KD*2);
  unsigned short* Wb2 = (unsigned short*)alloc((size_t)64*KD*2);
  unsigned short* xpb1 = (unsigned short*)alloc((size_t)N_NODES*128*2);
  float* as1    = (float*)alloc((size_t)N_NODES*2*4);
  float* ad1    = (float*)alloc((size_t)N_NODES*2*4);
  unsigned short* hb = (unsigned short*)alloc((size_t)N_NODES*128*2);
  float* as2    = (float*)alloc((size_t)N_NODES*2*4);
  float* ad2    = (float*)alloc((size_t)N_NODES*2*4);
  unsigned short* xpb2 = xpb1;                          // xpb1 dead after agg1

  packA_kernel  <<<NBLKA + WCB + 1, 256, 0, stream>>>(edges, M, W1, Wmu, Wst, Wb1, Wb2, erec,
                                                      asmu, admu, asst, adst, va);
  scanM1_kernel <<<MBS, 256, 0, stream>>>(M, bsumM);
  scanM23_kernel<<<MBS, 256, 0, stream>>>(M, bsumM, Mpos);
  packB_kernel  <<<NBLKA + MM2B, 256, 0, stream>>>(edges, Mpos, etmp,
                                                   x, Wb1, as1v, ad1v, xpb1, as1, ad1);
  bfin_kernel   <<<NBUCK, 256, 0, stream>>>(Mpos, etmp, rowptr, erec, as1, ad1);

  agg1_kernel  <<<(N_NODES+3)/4, 256, 0, stream>>>(rowptr, erec, (const uint4*)xpb1, b1, (uint4*)hb,
                                                   va, as2, ad2);
  packC_kernel <<<MM2B + WCE, 256, 0, stream>>>(hb, Wb2, xpb1, erec, as2, ad2);
  agg2_kernel  <<<(N_NODES+3)/4, 256, 0, stream>>>(rowptr, erec, (const uint4*)xpb2, bmu, bst, out);
}